// Round 8
// baseline (351.208 us; speedup 1.0000x reference)
//
#include <hip/hip_runtime.h>
#include <hip/hip_bf16.h>
#include <math.h>

#define NEG_SLOPE 0.2f

typedef short short8 __attribute__((ext_vector_type(8)));
typedef float floatx4 __attribute__((ext_vector_type(4)));

static __device__ __forceinline__ float bf2f(unsigned short u) {
  return __uint_as_float(((unsigned int)u) << 16);
}
static __device__ __forceinline__ unsigned short f2bf(float f) {
  unsigned int u = __float_as_uint(f);
  u = (u + 0x7fffu + ((u >> 16) & 1u)) >> 16;  // RNE
  return (unsigned short)u;
}
static __device__ __forceinline__ unsigned int pack2(float a, float b) {
  __hip_bfloat162 h = __float22bfloat162_rn(make_float2(a, b));  // v_cvt_pk_bf16_f32
  unsigned int u;
  __builtin_memcpy(&u, &h, 4);
  return u;
}

// ---------- prep: W1 -> bf16 transposed, deg init, ei -> ushort ----------
__global__ void prep_kernel(const float* __restrict__ W1, unsigned short* __restrict__ W1t,
                            int* __restrict__ deg, const int* __restrict__ ei,
                            unsigned short* __restrict__ src16, unsigned short* __restrict__ dst16,
                            int N, int E) {
  int i = blockIdx.x * 256 + threadIdx.x;
  if (i < 32768) {
    int k = i >> 6, c = i & 63;
    W1t[c * 512 + k] = f2bf(W1[i]);
  }
  int j = i - 32768;
  if (j >= 0 && j < N) deg[j] = 1;  // self-loop
  int e = i - 32768 - N;
  if (e >= 0 && e < E) {
    src16[e] = (unsigned short)ei[e];
    dst16[e] = (unsigned short)ei[E + e];
  }
}

// ---------- GEMM1 via MFMA, single-buffer LDS (8 blocks/CU) ----------
__global__ __launch_bounds__(256) void gemm1_mfma(const float* __restrict__ A,
                                                  const unsigned short* __restrict__ W1t,
                                                  const float* __restrict__ att_src,
                                                  const float* __restrict__ att_dst,
                                                  unsigned short* __restrict__ xlb,
                                                  float* __restrict__ a_src,
                                                  float* __restrict__ a_dst, int M) {
  __shared__ unsigned short As[64 * 72];  // pad 72: 2-way bank alias = free
  __shared__ unsigned short Bs[64 * 72];
  int tid = threadIdx.x;
  int w = tid >> 6, lane = tid & 63;
  int q = lane >> 4, cl = lane & 15;
  int row0 = blockIdx.x << 6;
  floatx4 acc[4] = {};

  int sr = tid >> 2;            // staging row/col 0..63
  int skq = (tid & 3) << 4;     // k offset 0,16,32,48
  int arow = row0 + sr;
  const float* Aptr = A + (size_t)arow * 512 + skq;
  const unsigned short* Bptr = W1t + sr * 512 + skq;
  unsigned short* AsW = As + sr * 72 + skq;
  unsigned short* BsW = Bs + sr * 72 + skq;

  for (int k0 = 0; k0 < 512; k0 += 64) {
    float4 f0 = make_float4(0.f, 0.f, 0.f, 0.f), f1 = f0, f2 = f0, f3 = f0;
    if (arow < M) {
      f0 = *(const float4*)(Aptr + k0);
      f1 = *(const float4*)(Aptr + k0 + 4);
      f2 = *(const float4*)(Aptr + k0 + 8);
      f3 = *(const float4*)(Aptr + k0 + 12);
    }
    uint4 b0 = *(const uint4*)(Bptr + k0);
    uint4 b1 = *(const uint4*)(Bptr + k0 + 8);
    __syncthreads();
    uint4 a0, a1;
    a0.x = pack2(f0.x, f0.y); a0.y = pack2(f0.z, f0.w);
    a0.z = pack2(f1.x, f1.y); a0.w = pack2(f1.z, f1.w);
    a1.x = pack2(f2.x, f2.y); a1.y = pack2(f2.z, f2.w);
    a1.z = pack2(f3.x, f3.y); a1.w = pack2(f3.z, f3.w);
    *(uint4*)(AsW) = a0;
    *(uint4*)(AsW + 8) = a1;
    *(uint4*)(BsW) = b0;
    *(uint4*)(BsW + 8) = b1;
    __syncthreads();
#pragma unroll
    for (int kk = 0; kk < 2; ++kk) {
      short8 af = *(const short8*)(As + (w * 16 + cl) * 72 + kk * 32 + q * 8);
#pragma unroll
      for (int t = 0; t < 4; ++t) {
        short8 bf = *(const short8*)(Bs + (t * 16 + cl) * 72 + kk * 32 + q * 8);
        acc[t] = __builtin_amdgcn_mfma_f32_16x16x32_bf16(af, bf, acc[t], 0, 0, 0);
      }
    }
  }

  // epilogue: C/D layout col = cl (within tile), row = q*4 + reg
  float asv[4], adv[4];
#pragma unroll
  for (int t = 0; t < 4; ++t) {
    asv[t] = att_src[t * 16 + cl];
    adv[t] = att_dst[t * 16 + cl];
  }
#pragma unroll
  for (int reg = 0; reg < 4; ++reg) {
    int r = row0 + w * 16 + q * 4 + reg;
    bool ok = r < M;
#pragma unroll
    for (int t = 0; t < 4; ++t) {
      float v = acc[t][reg];
      if (ok) xlb[(size_t)r * 64 + t * 16 + cl] = f2bf(v);
      float ps = v * asv[t];
      float pd = v * adv[t];
      ps += __shfl_xor(ps, 1); pd += __shfl_xor(pd, 1);
      ps += __shfl_xor(ps, 2); pd += __shfl_xor(pd, 2);
      ps += __shfl_xor(ps, 4); pd += __shfl_xor(pd, 4);
      if (ok && (cl & 7) == 0) {
        int h = t * 2 + (cl >> 3);
        a_src[r * 8 + h] = ps;
        a_dst[r * 8 + h] = pd;
      }
    }
  }
}

// ---------- XCD-sliced histogram (ushort dst) ----------
__global__ __launch_bounds__(256) void deg_hist_sliced(const unsigned short* __restrict__ dst16,
                                                       int* __restrict__ deg,
                                                       int E, int N, int ipc) {
  int slice = blockIdx.x & 7;
  int chunk = blockIdx.x >> 3;
  int lo = (int)(((long long)slice * N) >> 3);
  int hi = (int)(((long long)(slice + 1) * N) >> 3);
  int beg = chunk * ipc;
  int end = min(beg + ipc, E);
  for (int i = beg + threadIdx.x; i < end; i += 256) {
    int d = dst16[i];
    if (d >= lo && d < hi) atomicAdd(&deg[d], 1);
  }
}

// ---------- hierarchical scan ----------
__global__ __launch_bounds__(256) void partial_sums(const int* __restrict__ deg,
                                                    int* __restrict__ partials, int N) {
  __shared__ int ws[4];
  int base = blockIdx.x * 512;
  int tid = threadIdx.x;
  int i0 = base + tid * 2;
  int s = 0;
  if (i0 < N) s += deg[i0];
  if (i0 + 1 < N) s += deg[i0 + 1];
#pragma unroll
  for (int off = 32; off >= 1; off >>= 1) s += __shfl_xor(s, off, 64);
  if ((tid & 63) == 0) ws[tid >> 6] = s;
  __syncthreads();
  if (tid == 0) partials[blockIdx.x] = ws[0] + ws[1] + ws[2] + ws[3];
}

__global__ __launch_bounds__(256) void scan_partials(const int* __restrict__ partials,
                                                     int* __restrict__ blockoff,
                                                     int* __restrict__ rowptr, int nb, int N) {
  __shared__ int sums[256];
  int tid = threadIdx.x;
  int chunk = (nb + 255) >> 8;
  int start = tid * chunk, end = min(start + chunk, nb);
  int s = 0;
  for (int i = start; i < end; ++i) s += partials[i];
  sums[tid] = s;
  __syncthreads();
  for (int off = 1; off < 256; off <<= 1) {
    int t = (tid >= off) ? sums[tid - off] : 0;
    __syncthreads();
    sums[tid] += t;
    __syncthreads();
  }
  int run = (tid == 0) ? 0 : sums[tid - 1];
  for (int i = start; i < end; ++i) {
    blockoff[i] = run;
    run += partials[i];
  }
  if (tid == 255) rowptr[N] = sums[255];
}

__global__ __launch_bounds__(256) void scan_blocks(const int* __restrict__ deg,
                                                   const int* __restrict__ blockoff,
                                                   int* __restrict__ rowptr,
                                                   int* __restrict__ cursor, int N) {
  __shared__ int wavesum[4];
  int base = blockIdx.x * 512;
  int tid = threadIdx.x;
  int lane = tid & 63, wv = tid >> 6;
  int i0 = base + tid * 2;
  int d0 = (i0 < N) ? deg[i0] : 0;
  int d1 = (i0 + 1 < N) ? deg[i0 + 1] : 0;
  int s = d0 + d1;
  int v = s;
#pragma unroll
  for (int off = 1; off < 64; off <<= 1) {
    int t = __shfl_up(v, off, 64);
    if (lane >= off) v += t;
  }
  if (lane == 63) wavesum[wv] = v;
  __syncthreads();
  int woff = 0;
  for (int w = 0; w < wv; ++w) woff += wavesum[w];
  int excl = v - s + woff + blockoff[blockIdx.x];
  if (i0 < N) { rowptr[i0] = excl; cursor[i0] = excl; }
  if (i0 + 1 < N) { rowptr[i0 + 1] = excl + d0; cursor[i0 + 1] = excl + d0; }
}

// ---------- XCD-sliced scatter (ushort src/dst, ushort out) ----------
__global__ __launch_bounds__(256) void scatter_sliced(const unsigned short* __restrict__ src16,
                                                      const unsigned short* __restrict__ dst16,
                                                      int* __restrict__ cursor,
                                                      unsigned short* __restrict__ srcs,
                                                      int E, int N, int ipc) {
  int slice = blockIdx.x & 7;
  int chunk = blockIdx.x >> 3;
  int lo = (int)(((long long)slice * N) >> 3);
  int hi = (int)(((long long)(slice + 1) * N) >> 3);
  int total = E + N;
  int beg = chunk * ipc;
  int end = min(beg + ipc, total);
  for (int i = beg + threadIdx.x; i < end; i += 256) {
    int d = (i < E) ? (int)dst16[i] : (i - E);
    if (d >= lo && d < hi) {
      int s = (i < E) ? (int)src16[i] : d;
      int pos = atomicAdd(&cursor[d], 1);
      srcs[pos] = (unsigned short)s;
    }
  }
}

// ---------- layer-1 aggregation + wave-local layer-2 GEMM/att-coef ----------
// One independent wave per node (no block barrier). lane = channel, head = lane>>3.
// Epilogue: xl2 = (agg1+bias1)@W2 via 64-lane shuffle butterfly, all in-register.
__global__ __launch_bounds__(256) void agg1_wave(const int* __restrict__ rowptr,
                                                 const unsigned short* __restrict__ srcs,
                                                 const float* __restrict__ a_src,
                                                 const float* __restrict__ a_dst,
                                                 const unsigned short* __restrict__ xlb,
                                                 const float* __restrict__ bias1,
                                                 const float* __restrict__ W2,
                                                 const float* __restrict__ att_src2,
                                                 const float* __restrict__ att_dst2,
                                                 float* __restrict__ xl2,
                                                 float* __restrict__ a_src2,
                                                 float* __restrict__ a_dst2, int N) {
  int wave = (blockIdx.x * blockDim.x + threadIdx.x) >> 6;
  int lane = threadIdx.x & 63;
  if (wave >= N) return;
  int h = lane >> 3;
  int beg = rowptr[wave], end = rowptr[wave + 1];
  float ad = a_dst[wave * 8 + h];
  float den = 0.f, acc = 0.f;
  int p = beg;
  for (; p + 8 <= end; p += 8) {
    int s0 = srcs[p], s1 = srcs[p + 1], s2 = srcs[p + 2], s3 = srcs[p + 3];
    int s4 = srcs[p + 4], s5 = srcs[p + 5], s6 = srcs[p + 6], s7 = srcs[p + 7];
    float a0 = a_src[s0 * 8 + h], a1 = a_src[s1 * 8 + h];
    float a2 = a_src[s2 * 8 + h], a3 = a_src[s3 * 8 + h];
    float a4 = a_src[s4 * 8 + h], a5 = a_src[s5 * 8 + h];
    float a6 = a_src[s6 * 8 + h], a7 = a_src[s7 * 8 + h];
    float x0 = bf2f(xlb[(size_t)s0 * 64 + lane]);
    float x1 = bf2f(xlb[(size_t)s1 * 64 + lane]);
    float x2 = bf2f(xlb[(size_t)s2 * 64 + lane]);
    float x3 = bf2f(xlb[(size_t)s3 * 64 + lane]);
    float x4 = bf2f(xlb[(size_t)s4 * 64 + lane]);
    float x5 = bf2f(xlb[(size_t)s5 * 64 + lane]);
    float x6 = bf2f(xlb[(size_t)s6 * 64 + lane]);
    float x7 = bf2f(xlb[(size_t)s7 * 64 + lane]);
    a0 += ad; a1 += ad; a2 += ad; a3 += ad;
    a4 += ad; a5 += ad; a6 += ad; a7 += ad;
    a0 = a0 >= 0.f ? a0 : NEG_SLOPE * a0;
    a1 = a1 >= 0.f ? a1 : NEG_SLOPE * a1;
    a2 = a2 >= 0.f ? a2 : NEG_SLOPE * a2;
    a3 = a3 >= 0.f ? a3 : NEG_SLOPE * a3;
    a4 = a4 >= 0.f ? a4 : NEG_SLOPE * a4;
    a5 = a5 >= 0.f ? a5 : NEG_SLOPE * a5;
    a6 = a6 >= 0.f ? a6 : NEG_SLOPE * a6;
    a7 = a7 >= 0.f ? a7 : NEG_SLOPE * a7;
    float w0 = __expf(a0), w1 = __expf(a1), w2 = __expf(a2), w3 = __expf(a3);
    float w4 = __expf(a4), w5 = __expf(a5), w6 = __expf(a6), w7 = __expf(a7);
    den += ((w0 + w1) + (w2 + w3)) + ((w4 + w5) + (w6 + w7));
    acc += w0 * x0 + w1 * x1 + w2 * x2 + w3 * x3;
    acc += w4 * x4 + w5 * x5 + w6 * x6 + w7 * x7;
  }
  for (; p < end; ++p) {
    int s = srcs[p];
    float a = a_src[s * 8 + h] + ad;
    a = a >= 0.f ? a : NEG_SLOPE * a;
    float w = __expf(a);
    den += w;
    acc += w * bf2f(xlb[(size_t)s * 64 + lane]);
  }
  float hv = acc / (den + 1e-16f) + bias1[lane];

  // wave-local GEMM: t[c] = sum_k hv_k * W2[k][c]
  const float4* w2p = (const float4*)(W2 + lane * 16);
  float4 wa = w2p[0], wb = w2p[1], wc = w2p[2], wd = w2p[3];
  float t[16];
  t[0] = hv * wa.x; t[1] = hv * wa.y; t[2] = hv * wa.z; t[3] = hv * wa.w;
  t[4] = hv * wb.x; t[5] = hv * wb.y; t[6] = hv * wb.z; t[7] = hv * wb.w;
  t[8] = hv * wc.x; t[9] = hv * wc.y; t[10] = hv * wc.z; t[11] = hv * wc.w;
  t[12] = hv * wd.x; t[13] = hv * wd.y; t[14] = hv * wd.z; t[15] = hv * wd.w;
#pragma unroll
  for (int off = 1; off < 64; off <<= 1) {
#pragma unroll
    for (int c = 0; c < 16; ++c) t[c] += __shfl_xor(t[c], off);
  }
  int cl = lane & 15;
  float val = t[0];
#pragma unroll
  for (int c = 1; c < 16; ++c) val = (cl == c) ? t[c] : val;
  float ps = val * att_src2[cl];
  float pd = val * att_dst2[cl];
#pragma unroll
  for (int w = 8; w >= 1; w >>= 1) {
    ps += __shfl_xor(ps, w, 16);
    pd += __shfl_xor(pd, w, 16);
  }
  if (lane < 16) xl2[(size_t)wave * 16 + lane] = val;
  if (lane == 0) {
    a_src2[wave] = ps;
    a_dst2[wave] = pd;
  }
}

// ---------- layer-2 aggregation + bias2 + ELU + log_softmax ----------
// One wave per node: lane = j*16 + c (j = edge slot 0..3, c = class).
__global__ __launch_bounds__(256) void agg2_fin(const int* __restrict__ rowptr,
                                                const unsigned short* __restrict__ srcs,
                                                const float* __restrict__ a_src2,
                                                const float* __restrict__ a_dst2,
                                                const float* __restrict__ xl2,
                                                const float* __restrict__ bias2,
                                                float* __restrict__ out, int N) {
  int wave = (blockIdx.x * blockDim.x + threadIdx.x) >> 6;
  int lane = threadIdx.x & 63;
  if (wave >= N) return;
  int j = lane >> 4, c = lane & 15;
  int beg = rowptr[wave], end = rowptr[wave + 1];
  float ad = a_dst2[wave];
  float den = 0.f, acc = 0.f;
  for (int p0 = beg; p0 < end; p0 += 8) {
    int pe0 = p0 + j, pe1 = p0 + 4 + j;
    bool v0 = pe0 < end, v1 = pe1 < end;
    int s0 = v0 ? (int)srcs[pe0] : 0;
    int s1 = v1 ? (int)srcs[pe1] : 0;
    float a0 = a_src2[s0] + ad;
    float a1 = a_src2[s1] + ad;
    float x0 = xl2[(size_t)s0 * 16 + c];
    float x1 = xl2[(size_t)s1 * 16 + c];
    a0 = a0 >= 0.f ? a0 : NEG_SLOPE * a0;
    a1 = a1 >= 0.f ? a1 : NEG_SLOPE * a1;
    float w0 = v0 ? __expf(a0) : 0.f;
    float w1 = v1 ? __expf(a1) : 0.f;
    den += w0 + w1;
    acc += w0 * x0 + w1 * x1;
  }
  den += __shfl_xor(den, 16); den += __shfl_xor(den, 32);
  acc += __shfl_xor(acc, 16); acc += __shfl_xor(acc, 32);
  float o = acc / (den + 1e-16f) + bias2[c];
  o = o > 0.f ? o : expm1f(o);  // ELU alpha=1
  float mx = o;
#pragma unroll
  for (int w = 8; w >= 1; w >>= 1) mx = fmaxf(mx, __shfl_xor(mx, w, 16));
  float e = __expf(o - mx);
  float ssum = e;
#pragma unroll
  for (int w = 8; w >= 1; w >>= 1) ssum += __shfl_xor(ssum, w, 16);
  if (lane < 16) out[(size_t)wave * 16 + c] = o - mx - logf(ssum);
}

extern "C" void kernel_launch(void* const* d_in, const int* in_sizes, int n_in,
                              void* d_out, int out_size, void* d_ws, size_t ws_size,
                              hipStream_t stream) {
  const float* x        = (const float*)d_in[0];
  const int*   ei       = (const int*)d_in[1];
  const float* W1       = (const float*)d_in[2];
  const float* att_src1 = (const float*)d_in[3];
  const float* att_dst1 = (const float*)d_in[4];
  const float* bias1    = (const float*)d_in[5];
  const float* W2       = (const float*)d_in[6];
  const float* att_src2 = (const float*)d_in[7];
  const float* att_dst2 = (const float*)d_in[8];
  const float* bias2    = (const float*)d_in[9];
  float* out = (float*)d_out;

  int N = in_sizes[0] / 512;
  int E = in_sizes[1] / 2;
  int nb = (N + 511) / 512;

  char* wsp = (char*)d_ws;
  auto alloc = [&](size_t bytes) {
    char* p = wsp;
    wsp += (bytes + 255) & ~(size_t)255;
    return p;
  };
  unsigned short* xlb   = (unsigned short*)alloc((size_t)N * 64 * 2);
  unsigned short* W1t   = (unsigned short*)alloc((size_t)512 * 64 * 2);
  float* a_src1 = (float*)alloc((size_t)N * 8 * 4);
  float* a_dst1 = (float*)alloc((size_t)N * 8 * 4);
  float* xl2    = (float*)alloc((size_t)N * 16 * 4);
  float* a_src2 = (float*)alloc((size_t)N * 4);
  float* a_dst2 = (float*)alloc((size_t)N * 4);
  int* deg      = (int*)alloc((size_t)N * 4);
  int* rowptr   = (int*)alloc((size_t)(N + 1) * 4);
  int* cursor   = (int*)alloc((size_t)N * 4);
  int* partials = (int*)alloc((size_t)nb * 4);
  int* blockoff = (int*)alloc((size_t)nb * 4);
  unsigned short* src16 = (unsigned short*)alloc((size_t)E * 2);
  unsigned short* dst16 = (unsigned short*)alloc((size_t)E * 2);
  unsigned short* srcs  = (unsigned short*)alloc((size_t)(E + N) * 2);

  const int NCHUNK = 256;
  int ipc_h = (E + NCHUNK - 1) / NCHUNK;
  int ipc_s = (E + N + NCHUNK - 1) / NCHUNK;

  prep_kernel<<<(32768 + N + E + 255) / 256, 256, 0, stream>>>(W1, W1t, deg, ei, src16, dst16, N, E);
  deg_hist_sliced<<<NCHUNK * 8, 256, 0, stream>>>(dst16, deg, E, N, ipc_h);
  partial_sums<<<nb, 256, 0, stream>>>(deg, partials, N);
  scan_partials<<<1, 256, 0, stream>>>(partials, blockoff, rowptr, nb, N);
  scan_blocks<<<nb, 256, 0, stream>>>(deg, blockoff, rowptr, cursor, N);
  scatter_sliced<<<NCHUNK * 8, 256, 0, stream>>>(src16, dst16, cursor, srcs, E, N, ipc_s);

  gemm1_mfma<<<(N + 63) / 64, 256, 0, stream>>>(x, W1t, att_src1, att_dst1,
                                                xlb, a_src1, a_dst1, N);
  agg1_wave<<<((size_t)N * 64 + 255) / 256, 256, 0, stream>>>(rowptr, srcs, a_src1, a_dst1, xlb,
                                                              bias1, W2, att_src2, att_dst2,
                                                              xl2, a_src2, a_dst2, N);
  agg2_fin<<<((size_t)N * 64 + 255) / 256, 256, 0, stream>>>(rowptr, srcs, a_src2, a_dst2,
                                                             xl2, bias2, out, N);
}

// Round 9
// 331.075 us; speedup vs baseline: 1.0608x; 1.0608x over previous
//
#include <hip/hip_runtime.h>
#include <hip/hip_bf16.h>
#include <math.h>

#define NEG_SLOPE 0.2f

typedef short short8 __attribute__((ext_vector_type(8)));
typedef float floatx4 __attribute__((ext_vector_type(4)));

static __device__ __forceinline__ float bf2f(unsigned short u) {
  return __uint_as_float(((unsigned int)u) << 16);
}
static __device__ __forceinline__ unsigned short f2bf(float f) {
  unsigned int u = __float_as_uint(f);
  u = (u + 0x7fffu + ((u >> 16) & 1u)) >> 16;  // RNE
  return (unsigned short)u;
}
static __device__ __forceinline__ unsigned int pack2(float a, float b) {
  __hip_bfloat162 h = __float22bfloat162_rn(make_float2(a, b));  // v_cvt_pk_bf16_f32
  unsigned int u;
  __builtin_memcpy(&u, &h, 4);
  return u;
}

// ---------- prep: W1 -> bf16 transposed, deg init, ei -> ushort ----------
__global__ void prep_kernel(const float* __restrict__ W1, unsigned short* __restrict__ W1t,
                            int* __restrict__ deg, const int* __restrict__ ei,
                            unsigned short* __restrict__ src16, unsigned short* __restrict__ dst16,
                            int N, int E) {
  int i = blockIdx.x * 256 + threadIdx.x;
  if (i < 32768) {
    int k = i >> 6, c = i & 63;
    W1t[c * 512 + k] = f2bf(W1[i]);
  }
  int j = i - 32768;
  if (j >= 0 && j < N) deg[j] = 1;  // self-loop
  int e = i - 32768 - N;
  if (e >= 0 && e < E) {
    src16[e] = (unsigned short)ei[e];
    dst16[e] = (unsigned short)ei[E + e];
  }
}

// ---------- GEMM1 via MFMA, single-buffer LDS ----------
__global__ __launch_bounds__(256) void gemm1_mfma(const float* __restrict__ A,
                                                  const unsigned short* __restrict__ W1t,
                                                  const float* __restrict__ att_src,
                                                  const float* __restrict__ att_dst,
                                                  unsigned short* __restrict__ xlb,
                                                  float* __restrict__ a_src,
                                                  float* __restrict__ a_dst, int M) {
  __shared__ unsigned short As[64 * 72];  // pad 72: 2-way bank alias = free
  __shared__ unsigned short Bs[64 * 72];
  int tid = threadIdx.x;
  int w = tid >> 6, lane = tid & 63;
  int q = lane >> 4, cl = lane & 15;
  int row0 = blockIdx.x << 6;
  floatx4 acc[4] = {};

  int sr = tid >> 2;            // staging row/col 0..63
  int skq = (tid & 3) << 4;     // k offset 0,16,32,48
  int arow = row0 + sr;
  const float* Aptr = A + (size_t)arow * 512 + skq;
  const unsigned short* Bptr = W1t + sr * 512 + skq;
  unsigned short* AsW = As + sr * 72 + skq;
  unsigned short* BsW = Bs + sr * 72 + skq;

  for (int k0 = 0; k0 < 512; k0 += 64) {
    float4 f0 = make_float4(0.f, 0.f, 0.f, 0.f), f1 = f0, f2 = f0, f3 = f0;
    if (arow < M) {
      f0 = *(const float4*)(Aptr + k0);
      f1 = *(const float4*)(Aptr + k0 + 4);
      f2 = *(const float4*)(Aptr + k0 + 8);
      f3 = *(const float4*)(Aptr + k0 + 12);
    }
    uint4 b0 = *(const uint4*)(Bptr + k0);
    uint4 b1 = *(const uint4*)(Bptr + k0 + 8);
    __syncthreads();
    uint4 a0, a1;
    a0.x = pack2(f0.x, f0.y); a0.y = pack2(f0.z, f0.w);
    a0.z = pack2(f1.x, f1.y); a0.w = pack2(f1.z, f1.w);
    a1.x = pack2(f2.x, f2.y); a1.y = pack2(f2.z, f2.w);
    a1.z = pack2(f3.x, f3.y); a1.w = pack2(f3.z, f3.w);
    *(uint4*)(AsW) = a0;
    *(uint4*)(AsW + 8) = a1;
    *(uint4*)(BsW) = b0;
    *(uint4*)(BsW + 8) = b1;
    __syncthreads();
#pragma unroll
    for (int kk = 0; kk < 2; ++kk) {
      short8 af = *(const short8*)(As + (w * 16 + cl) * 72 + kk * 32 + q * 8);
#pragma unroll
      for (int t = 0; t < 4; ++t) {
        short8 bf = *(const short8*)(Bs + (t * 16 + cl) * 72 + kk * 32 + q * 8);
        acc[t] = __builtin_amdgcn_mfma_f32_16x16x32_bf16(af, bf, acc[t], 0, 0, 0);
      }
    }
  }

  // epilogue: C/D layout col = cl (within tile), row = q*4 + reg
  float asv[4], adv[4];
#pragma unroll
  for (int t = 0; t < 4; ++t) {
    asv[t] = att_src[t * 16 + cl];
    adv[t] = att_dst[t * 16 + cl];
  }
#pragma unroll
  for (int reg = 0; reg < 4; ++reg) {
    int r = row0 + w * 16 + q * 4 + reg;
    bool ok = r < M;
#pragma unroll
    for (int t = 0; t < 4; ++t) {
      float v = acc[t][reg];
      if (ok) xlb[(size_t)r * 64 + t * 16 + cl] = f2bf(v);
      float ps = v * asv[t];
      float pd = v * adv[t];
      ps += __shfl_xor(ps, 1); pd += __shfl_xor(pd, 1);
      ps += __shfl_xor(ps, 2); pd += __shfl_xor(pd, 2);
      ps += __shfl_xor(ps, 4); pd += __shfl_xor(pd, 4);
      if (ok && (cl & 7) == 0) {
        int h = t * 2 + (cl >> 3);
        a_src[r * 8 + h] = ps;
        a_dst[r * 8 + h] = pd;
      }
    }
  }
}

// ---------- XCD-sliced histogram (ushort dst) ----------
__global__ __launch_bounds__(256) void deg_hist_sliced(const unsigned short* __restrict__ dst16,
                                                       int* __restrict__ deg,
                                                       int E, int N, int ipc) {
  int slice = blockIdx.x & 7;
  int chunk = blockIdx.x >> 3;
  int lo = (int)(((long long)slice * N) >> 3);
  int hi = (int)(((long long)(slice + 1) * N) >> 3);
  int beg = chunk * ipc;
  int end = min(beg + ipc, E);
  for (int i = beg + threadIdx.x; i < end; i += 256) {
    int d = dst16[i];
    if (d >= lo && d < hi) atomicAdd(&deg[d], 1);
  }
}

// ---------- hierarchical scan ----------
__global__ __launch_bounds__(256) void partial_sums(const int* __restrict__ deg,
                                                    int* __restrict__ partials, int N) {
  __shared__ int ws[4];
  int base = blockIdx.x * 512;
  int tid = threadIdx.x;
  int i0 = base + tid * 2;
  int s = 0;
  if (i0 < N) s += deg[i0];
  if (i0 + 1 < N) s += deg[i0 + 1];
#pragma unroll
  for (int off = 32; off >= 1; off >>= 1) s += __shfl_xor(s, off, 64);
  if ((tid & 63) == 0) ws[tid >> 6] = s;
  __syncthreads();
  if (tid == 0) partials[blockIdx.x] = ws[0] + ws[1] + ws[2] + ws[3];
}

__global__ __launch_bounds__(256) void scan_partials(const int* __restrict__ partials,
                                                     int* __restrict__ blockoff,
                                                     int* __restrict__ rowptr, int nb, int N) {
  __shared__ int sums[256];
  int tid = threadIdx.x;
  int chunk = (nb + 255) >> 8;
  int start = tid * chunk, end = min(start + chunk, nb);
  int s = 0;
  for (int i = start; i < end; ++i) s += partials[i];
  sums[tid] = s;
  __syncthreads();
  for (int off = 1; off < 256; off <<= 1) {
    int t = (tid >= off) ? sums[tid - off] : 0;
    __syncthreads();
    sums[tid] += t;
    __syncthreads();
  }
  int run = (tid == 0) ? 0 : sums[tid - 1];
  for (int i = start; i < end; ++i) {
    blockoff[i] = run;
    run += partials[i];
  }
  if (tid == 255) rowptr[N] = sums[255];
}

__global__ __launch_bounds__(256) void scan_blocks(const int* __restrict__ deg,
                                                   const int* __restrict__ blockoff,
                                                   int* __restrict__ rowptr,
                                                   int* __restrict__ cursor, int N) {
  __shared__ int wavesum[4];
  int base = blockIdx.x * 512;
  int tid = threadIdx.x;
  int lane = tid & 63, wv = tid >> 6;
  int i0 = base + tid * 2;
  int d0 = (i0 < N) ? deg[i0] : 0;
  int d1 = (i0 + 1 < N) ? deg[i0 + 1] : 0;
  int s = d0 + d1;
  int v = s;
#pragma unroll
  for (int off = 1; off < 64; off <<= 1) {
    int t = __shfl_up(v, off, 64);
    if (lane >= off) v += t;
  }
  if (lane == 63) wavesum[wv] = v;
  __syncthreads();
  int woff = 0;
  for (int w = 0; w < wv; ++w) woff += wavesum[w];
  int excl = v - s + woff + blockoff[blockIdx.x];
  if (i0 < N) { rowptr[i0] = excl; cursor[i0] = excl; }
  if (i0 + 1 < N) { rowptr[i0 + 1] = excl + d0; cursor[i0 + 1] = excl + d0; }
}

// ---------- XCD-sliced scatter (ushort) ----------
__global__ __launch_bounds__(256) void scatter_sliced(const unsigned short* __restrict__ src16,
                                                      const unsigned short* __restrict__ dst16,
                                                      int* __restrict__ cursor,
                                                      unsigned short* __restrict__ srcs,
                                                      int E, int N, int ipc) {
  int slice = blockIdx.x & 7;
  int chunk = blockIdx.x >> 3;
  int lo = (int)(((long long)slice * N) >> 3);
  int hi = (int)(((long long)(slice + 1) * N) >> 3);
  int total = E + N;
  int beg = chunk * ipc;
  int end = min(beg + ipc, total);
  for (int i = beg + threadIdx.x; i < end; i += 256) {
    int d = (i < E) ? (int)dst16[i] : (i - E);
    if (d >= lo && d < hi) {
      int s = (i < E) ? (int)src16[i] : d;
      int pos = atomicAdd(&cursor[d], 1);
      srcs[pos] = (unsigned short)s;
    }
  }
}

// ---------- layer-1 aggregation: one wave per node, scalarized indices ----------
// Edge index p is wave-uniform -> broadcast srcs via v_readlane into SGPRs, so
// a_src/xlb gathers become saddr-form loads (SGPR base + small VGPR offset).
__global__ __launch_bounds__(256) void agg1_csr(const int* __restrict__ rowptr,
                                                const unsigned short* __restrict__ srcs,
                                                const float* __restrict__ a_src,
                                                const float* __restrict__ a_dst,
                                                const unsigned short* __restrict__ xlb,
                                                float* __restrict__ agg1, int N) {
  int wave = (blockIdx.x * blockDim.x + threadIdx.x) >> 6;
  int lane = threadIdx.x & 63;
  if (wave >= N) return;
  int h = lane >> 3;
  int beg = rowptr[wave], end = rowptr[wave + 1];
  float ad = a_dst[wave * 8 + h];
  float den = 0.f, acc = 0.f;
  int p = beg;
  for (; p + 8 <= end; p += 8) {
    int myv = (int)srcs[p + (lane & 7)];  // coalesced; lanes 0..7 hold the 8 edges
    int s0 = __builtin_amdgcn_readlane(myv, 0);
    int s1 = __builtin_amdgcn_readlane(myv, 1);
    int s2 = __builtin_amdgcn_readlane(myv, 2);
    int s3 = __builtin_amdgcn_readlane(myv, 3);
    int s4 = __builtin_amdgcn_readlane(myv, 4);
    int s5 = __builtin_amdgcn_readlane(myv, 5);
    int s6 = __builtin_amdgcn_readlane(myv, 6);
    int s7 = __builtin_amdgcn_readlane(myv, 7);
    float a0 = a_src[s0 * 8 + h], a1 = a_src[s1 * 8 + h];
    float a2 = a_src[s2 * 8 + h], a3 = a_src[s3 * 8 + h];
    float a4 = a_src[s4 * 8 + h], a5 = a_src[s5 * 8 + h];
    float a6 = a_src[s6 * 8 + h], a7 = a_src[s7 * 8 + h];
    float x0 = bf2f(xlb[(size_t)s0 * 64 + lane]);
    float x1 = bf2f(xlb[(size_t)s1 * 64 + lane]);
    float x2 = bf2f(xlb[(size_t)s2 * 64 + lane]);
    float x3 = bf2f(xlb[(size_t)s3 * 64 + lane]);
    float x4 = bf2f(xlb[(size_t)s4 * 64 + lane]);
    float x5 = bf2f(xlb[(size_t)s5 * 64 + lane]);
    float x6 = bf2f(xlb[(size_t)s6 * 64 + lane]);
    float x7 = bf2f(xlb[(size_t)s7 * 64 + lane]);
    a0 += ad; a1 += ad; a2 += ad; a3 += ad;
    a4 += ad; a5 += ad; a6 += ad; a7 += ad;
    a0 = a0 >= 0.f ? a0 : NEG_SLOPE * a0;
    a1 = a1 >= 0.f ? a1 : NEG_SLOPE * a1;
    a2 = a2 >= 0.f ? a2 : NEG_SLOPE * a2;
    a3 = a3 >= 0.f ? a3 : NEG_SLOPE * a3;
    a4 = a4 >= 0.f ? a4 : NEG_SLOPE * a4;
    a5 = a5 >= 0.f ? a5 : NEG_SLOPE * a5;
    a6 = a6 >= 0.f ? a6 : NEG_SLOPE * a6;
    a7 = a7 >= 0.f ? a7 : NEG_SLOPE * a7;
    float w0 = __expf(a0), w1 = __expf(a1), w2 = __expf(a2), w3 = __expf(a3);
    float w4 = __expf(a4), w5 = __expf(a5), w6 = __expf(a6), w7 = __expf(a7);
    den += ((w0 + w1) + (w2 + w3)) + ((w4 + w5) + (w6 + w7));
    acc += w0 * x0 + w1 * x1 + w2 * x2 + w3 * x3;
    acc += w4 * x4 + w5 * x5 + w6 * x6 + w7 * x7;
  }
  for (; p < end; ++p) {
    int s = __builtin_amdgcn_readfirstlane((int)srcs[p]);
    float a = a_src[s * 8 + h] + ad;
    a = a >= 0.f ? a : NEG_SLOPE * a;
    float w = __expf(a);
    den += w;
    acc += w * bf2f(xlb[(size_t)s * 64 + lane]);
  }
  agg1[(size_t)wave * 64 + lane] = acc / (den + 1e-16f);
}

// ---------- layer-2 GEMM (bias1 fused) + attention coefs ----------
__global__ __launch_bounds__(256) void gemm2_prep(const float* __restrict__ agg1,
                                                  const float* __restrict__ bias1,
                                                  const float* __restrict__ W2,
                                                  const float* __restrict__ att_src2,
                                                  const float* __restrict__ att_dst2,
                                                  float* __restrict__ xl2,
                                                  float* __restrict__ a_src2,
                                                  float* __restrict__ a_dst2, int N) {
  __shared__ float hs[16 * 68];
  int tid = threadIdx.x;
  int n0 = blockIdx.x << 4;
  {
    int node = tid >> 4;
    int off = (tid & 15) << 2;
    int nn = n0 + node;
    float4 v = make_float4(0.f, 0.f, 0.f, 0.f);
    if (nn < N) {
      v = *(const float4*)(agg1 + (size_t)nn * 64 + off);
      float4 b = *(const float4*)(bias1 + off);
      v.x += b.x; v.y += b.y; v.z += b.z; v.w += b.w;
    }
    *(float4*)(hs + node * 68 + off) = v;
  }
  __syncthreads();
  int t = tid >> 4, c = tid & 15;
  int n = n0 + t;
  if (n >= N) return;
  float sum = 0.f;
#pragma unroll
  for (int k = 0; k < 64; ++k) sum += hs[t * 68 + k] * W2[k * 16 + c];
  xl2[(size_t)n * 16 + c] = sum;
  float ps = sum * att_src2[c];
  float pd = sum * att_dst2[c];
#pragma unroll
  for (int w = 8; w >= 1; w >>= 1) {
    ps += __shfl_xor(ps, w, 16);
    pd += __shfl_xor(pd, w, 16);
  }
  if (c == 0) {
    a_src2[n] = ps;
    a_dst2[n] = pd;
  }
}

// ---------- layer-2 aggregation + bias2 + ELU + log_softmax ----------
// 16 lanes per node (4 nodes per wave); lane = output class; unroll-8.
__global__ __launch_bounds__(256) void agg2_fin(const int* __restrict__ rowptr,
                                                const unsigned short* __restrict__ srcs,
                                                const float* __restrict__ a_src2,
                                                const float* __restrict__ a_dst2,
                                                const float* __restrict__ xl2,
                                                const float* __restrict__ bias2,
                                                float* __restrict__ out, int N) {
  int t = blockIdx.x * blockDim.x + threadIdx.x;
  int node = t >> 4;
  int c = t & 15;
  if (node >= N) return;
  int beg = rowptr[node], end = rowptr[node + 1];
  float ad = a_dst2[node];
  float den = 0.f, acc = 0.f;
  int p = beg;
  for (; p + 8 <= end; p += 8) {
    int s0 = srcs[p], s1 = srcs[p + 1], s2 = srcs[p + 2], s3 = srcs[p + 3];
    int s4 = srcs[p + 4], s5 = srcs[p + 5], s6 = srcs[p + 6], s7 = srcs[p + 7];
    float a0 = a_src2[s0], a1 = a_src2[s1], a2 = a_src2[s2], a3 = a_src2[s3];
    float a4 = a_src2[s4], a5 = a_src2[s5], a6 = a_src2[s6], a7 = a_src2[s7];
    float x0 = xl2[(size_t)s0 * 16 + c], x1 = xl2[(size_t)s1 * 16 + c];
    float x2 = xl2[(size_t)s2 * 16 + c], x3 = xl2[(size_t)s3 * 16 + c];
    float x4 = xl2[(size_t)s4 * 16 + c], x5 = xl2[(size_t)s5 * 16 + c];
    float x6 = xl2[(size_t)s6 * 16 + c], x7 = xl2[(size_t)s7 * 16 + c];
    a0 += ad; a1 += ad; a2 += ad; a3 += ad;
    a4 += ad; a5 += ad; a6 += ad; a7 += ad;
    a0 = a0 >= 0.f ? a0 : NEG_SLOPE * a0;
    a1 = a1 >= 0.f ? a1 : NEG_SLOPE * a1;
    a2 = a2 >= 0.f ? a2 : NEG_SLOPE * a2;
    a3 = a3 >= 0.f ? a3 : NEG_SLOPE * a3;
    a4 = a4 >= 0.f ? a4 : NEG_SLOPE * a4;
    a5 = a5 >= 0.f ? a5 : NEG_SLOPE * a5;
    a6 = a6 >= 0.f ? a6 : NEG_SLOPE * a6;
    a7 = a7 >= 0.f ? a7 : NEG_SLOPE * a7;
    float w0 = __expf(a0), w1 = __expf(a1), w2 = __expf(a2), w3 = __expf(a3);
    float w4 = __expf(a4), w5 = __expf(a5), w6 = __expf(a6), w7 = __expf(a7);
    den += ((w0 + w1) + (w2 + w3)) + ((w4 + w5) + (w6 + w7));
    acc += w0 * x0 + w1 * x1 + w2 * x2 + w3 * x3;
    acc += w4 * x4 + w5 * x5 + w6 * x6 + w7 * x7;
  }
  for (; p < end; ++p) {
    int s = srcs[p];
    float a = a_src2[s] + ad;
    a = a >= 0.f ? a : NEG_SLOPE * a;
    float w = __expf(a);
    den += w;
    acc += w * xl2[(size_t)s * 16 + c];
  }
  float o = acc / (den + 1e-16f) + bias2[c];
  o = o > 0.f ? o : expm1f(o);  // ELU alpha=1
  float mx = o;
#pragma unroll
  for (int w = 8; w >= 1; w >>= 1) mx = fmaxf(mx, __shfl_xor(mx, w, 16));
  float e = __expf(o - mx);
  float ssum = e;
#pragma unroll
  for (int w = 8; w >= 1; w >>= 1) ssum += __shfl_xor(ssum, w, 16);
  out[(size_t)node * 16 + c] = o - mx - logf(ssum);
}

extern "C" void kernel_launch(void* const* d_in, const int* in_sizes, int n_in,
                              void* d_out, int out_size, void* d_ws, size_t ws_size,
                              hipStream_t stream) {
  const float* x        = (const float*)d_in[0];
  const int*   ei       = (const int*)d_in[1];
  const float* W1       = (const float*)d_in[2];
  const float* att_src1 = (const float*)d_in[3];
  const float* att_dst1 = (const float*)d_in[4];
  const float* bias1    = (const float*)d_in[5];
  const float* W2       = (const float*)d_in[6];
  const float* att_src2 = (const float*)d_in[7];
  const float* att_dst2 = (const float*)d_in[8];
  const float* bias2    = (const float*)d_in[9];
  float* out = (float*)d_out;

  int N = in_sizes[0] / 512;
  int E = in_sizes[1] / 2;
  int nb = (N + 511) / 512;

  char* wsp = (char*)d_ws;
  auto alloc = [&](size_t bytes) {
    char* p = wsp;
    wsp += (bytes + 255) & ~(size_t)255;
    return p;
  };
  unsigned short* xlb   = (unsigned short*)alloc((size_t)N * 64 * 2);
  unsigned short* W1t   = (unsigned short*)alloc((size_t)512 * 64 * 2);
  float* a_src1 = (float*)alloc((size_t)N * 8 * 4);
  float* a_dst1 = (float*)alloc((size_t)N * 8 * 4);
  float* agg1   = (float*)alloc((size_t)N * 64 * 4);
  float* xl2    = (float*)alloc((size_t)N * 16 * 4);
  float* a_src2 = (float*)alloc((size_t)N * 4);
  float* a_dst2 = (float*)alloc((size_t)N * 4);
  int* deg      = (int*)alloc((size_t)N * 4);
  int* rowptr   = (int*)alloc((size_t)(N + 1) * 4);
  int* cursor   = (int*)alloc((size_t)N * 4);
  int* partials = (int*)alloc((size_t)nb * 4);
  int* blockoff = (int*)alloc((size_t)nb * 4);
  unsigned short* src16 = (unsigned short*)alloc((size_t)E * 2);
  unsigned short* dst16 = (unsigned short*)alloc((size_t)E * 2);
  unsigned short* srcs  = (unsigned short*)alloc((size_t)(E + N) * 2);

  const int NCHUNK = 256;
  int ipc_h = (E + NCHUNK - 1) / NCHUNK;
  int ipc_s = (E + N + NCHUNK - 1) / NCHUNK;

  prep_kernel<<<(32768 + N + E + 255) / 256, 256, 0, stream>>>(W1, W1t, deg, ei, src16, dst16, N, E);
  deg_hist_sliced<<<NCHUNK * 8, 256, 0, stream>>>(dst16, deg, E, N, ipc_h);
  partial_sums<<<nb, 256, 0, stream>>>(deg, partials, N);
  scan_partials<<<1, 256, 0, stream>>>(partials, blockoff, rowptr, nb, N);
  scan_blocks<<<nb, 256, 0, stream>>>(deg, blockoff, rowptr, cursor, N);
  scatter_sliced<<<NCHUNK * 8, 256, 0, stream>>>(src16, dst16, cursor, srcs, E, N, ipc_s);

  gemm1_mfma<<<(N + 63) / 64, 256, 0, stream>>>(x, W1t, att_src1, att_dst1,
                                                xlb, a_src1, a_dst1, N);
  agg1_csr<<<((size_t)N * 64 + 255) / 256, 256, 0, stream>>>(rowptr, srcs, a_src1, a_dst1,
                                                             xlb, agg1, N);
  gemm2_prep<<<(N + 15) / 16, 256, 0, stream>>>(agg1, bias1, W2, att_src2, att_dst2,
                                                xl2, a_src2, a_dst2, N);
  agg2_fin<<<((size_t)N * 16 + 255) / 256, 256, 0, stream>>>(rowptr, srcs, a_src2, a_dst2,
                                                             xl2, bias2, out, N);
}